// Round 1
// baseline (1317.675 us; speedup 1.0000x reference)
//
#include <hip/hip_runtime.h>
#include <hip/hip_bf16.h>
#include <math.h>

// Problem constants
#define BB 2
#define TT 2048
#define DD 1024
#define HH 16
#define DK 64

// ---------------------------------------------------------------------------
// GEMM: C[M,N] = A[M,K] @ Bw[N,K]^T (+ bias). Both operands row-major,
// W accessed row-wise (torch Linear semantics). 64x64 tile, BK=16,
// 256 threads, 4x4 microtile, LDS stride 68 (16B-aligned rows, no >2-way
// bank conflicts).
// ---------------------------------------------------------------------------
__global__ __launch_bounds__(256) void gemm_nt_kernel(
    const float* __restrict__ A, const float* __restrict__ Bw,
    const float* __restrict__ bias, float* __restrict__ C,
    int M, int N, int K, int hasBias)
{
    __shared__ float As[16][68];  // [k][m]
    __shared__ float Bs[16][68];  // [k][n]
    const int t  = threadIdx.x;
    const int n0 = blockIdx.x * 64;
    const int m0 = blockIdx.y * 64;
    const int tx = t & 15;        // n-dir
    const int ty = t >> 4;        // m-dir

    const int lrow = t >> 2;          // 0..63
    const int lk   = (t & 3) * 4;     // 0,4,8,12

    const float* Aptr = A + (size_t)(m0 + lrow) * K + lk;
    const float* Bptr = Bw + (size_t)(n0 + lrow) * K + lk;

    float acc[4][4];
#pragma unroll
    for (int i = 0; i < 4; ++i)
#pragma unroll
        for (int j = 0; j < 4; ++j) acc[i][j] = 0.f;

    for (int k0 = 0; k0 < K; k0 += 16) {
        float4 a4 = *(const float4*)(Aptr + k0);
        float4 b4 = *(const float4*)(Bptr + k0);
        __syncthreads();
        As[lk + 0][lrow] = a4.x;
        As[lk + 1][lrow] = a4.y;
        As[lk + 2][lrow] = a4.z;
        As[lk + 3][lrow] = a4.w;
        Bs[lk + 0][lrow] = b4.x;
        Bs[lk + 1][lrow] = b4.y;
        Bs[lk + 2][lrow] = b4.z;
        Bs[lk + 3][lrow] = b4.w;
        __syncthreads();
#pragma unroll
        for (int kk = 0; kk < 16; ++kk) {
            float4 av = *(const float4*)&As[kk][ty * 4];
            float4 bv = *(const float4*)&Bs[kk][tx * 4];
            acc[0][0] += av.x * bv.x; acc[0][1] += av.x * bv.y;
            acc[0][2] += av.x * bv.z; acc[0][3] += av.x * bv.w;
            acc[1][0] += av.y * bv.x; acc[1][1] += av.y * bv.y;
            acc[1][2] += av.y * bv.z; acc[1][3] += av.y * bv.w;
            acc[2][0] += av.z * bv.x; acc[2][1] += av.z * bv.y;
            acc[2][2] += av.z * bv.z; acc[2][3] += av.z * bv.w;
            acc[3][0] += av.w * bv.x; acc[3][1] += av.w * bv.y;
            acc[3][2] += av.w * bv.z; acc[3][3] += av.w * bv.w;
        }
    }

    const int col = n0 + tx * 4;
    float4 bv4 = make_float4(0.f, 0.f, 0.f, 0.f);
    if (hasBias) bv4 = *(const float4*)(bias + col);
#pragma unroll
    for (int i = 0; i < 4; ++i) {
        const int row = m0 + ty * 4 + i;
        float4 r;
        r.x = acc[i][0] + bv4.x;
        r.y = acc[i][1] + bv4.y;
        r.z = acc[i][2] + bv4.z;
        r.w = acc[i][3] + bv4.w;
        *(float4*)&C[(size_t)row * N + col] = r;
    }
}

// ---------------------------------------------------------------------------
// Normalize Q in place: each 64-wide head segment / max(||.||, 1e-12).
// One wave per segment, 4 segments per block.
// ---------------------------------------------------------------------------
__global__ __launch_bounds__(256) void norm_q_kernel(float* __restrict__ Q)
{
    const int seg  = blockIdx.x * 4 + (threadIdx.x >> 6);
    const int lane = threadIdx.x & 63;
    const int row  = seg >> 4;   // / H
    const int h    = seg & 15;   // % H
    float* p = Q + (size_t)row * DD + h * DK + lane;
    float v = *p;
    float s = v * v;
    s += __shfl_xor(s, 1);
    s += __shfl_xor(s, 2);
    s += __shfl_xor(s, 4);
    s += __shfl_xor(s, 8);
    s += __shfl_xor(s, 16);
    s += __shfl_xor(s, 32);
    float n = sqrtf(s);
    *p = v / fmaxf(n, 1e-12f);
}

// ---------------------------------------------------------------------------
// Normalize K and transpose into Kt[b][h][dk][T] so attention K-tile loads
// are fully coalesced along T.
// ---------------------------------------------------------------------------
__global__ __launch_bounds__(256) void norm_k_transpose_kernel(
    const float* __restrict__ K0, float* __restrict__ Kt)
{
    const int seg  = blockIdx.x * 4 + (threadIdx.x >> 6);
    const int lane = threadIdx.x & 63;
    const int row  = seg >> 4;   // b*T + t
    const int h    = seg & 15;
    float v = K0[(size_t)row * DD + h * DK + lane];
    float s = v * v;
    s += __shfl_xor(s, 1);
    s += __shfl_xor(s, 2);
    s += __shfl_xor(s, 4);
    s += __shfl_xor(s, 8);
    s += __shfl_xor(s, 16);
    s += __shfl_xor(s, 32);
    float n = sqrtf(s);
    const int b  = row >> 11;       // / T
    const int tt = row & 2047;      // % T
    Kt[((size_t)((b * HH + h) * DK + lane)) * TT + tt] = v / fmaxf(n, 1e-12f);
}

// ---------------------------------------------------------------------------
// Fused angular attention. Grid: (T/32, H, B); block 256.
// Per block: 32 queries, stream K/V in 64-key tiles.
// Thread t: qi = t>>3 (query within tile), owns 8 consecutive cols c0..c0+7.
// ---------------------------------------------------------------------------
__global__ __launch_bounds__(256) void attn_kernel(
    const float* __restrict__ Qn, const float* __restrict__ Kt,
    const float* __restrict__ V0, float* __restrict__ Oa)
{
    __shared__ float Qs[32][68];   // [q][dim]
    __shared__ float Kts[64][68];  // [dim][key]
    __shared__ float Vs[64][68];   // [key][dim]
    __shared__ float Ws[32][68];   // [q][key]

    const int t  = threadIdx.x;
    const int q0 = blockIdx.x * 32;
    const int h  = blockIdx.y;
    const int b  = blockIdx.z;

    // Load + keep Q tile (already normalized)
    {
        const int qrow = t >> 3;
        const float* src = Qn + (size_t)(b * TT + q0 + qrow) * DD + h * DK;
#pragma unroll
        for (int r = 0; r < 2; ++r) {
            const int off = ((t & 7) * 2 + r) * 4;
            *(float4*)&Qs[qrow][off] = *(const float4*)(src + off);
        }
    }

    const int qi = t >> 3;
    const int c0 = (t & 7) * 8;

    float o[8];
#pragma unroll
    for (int j = 0; j < 8; ++j) o[j] = 0.f;
    float rowsum = 0.f;

    const float* kbase = Kt + ((size_t)((b * HH + h) * DK)) * TT;

    for (int k0 = 0; k0 < TT; k0 += 64) {
        __syncthreads();  // previous tile fully consumed
        // load K tile transposed: Kts[dim][key]
        {
            const int dim = t >> 2;
            const float* ksrc = kbase + (size_t)dim * TT + k0;
#pragma unroll
            for (int r = 0; r < 4; ++r) {
                const int off = (t & 3) * 4 + r * 16;
                *(float4*)&Kts[dim][off] = *(const float4*)(ksrc + off);
            }
            const int key = t >> 2;
            const float* vsrc = V0 + (size_t)(b * TT + k0 + key) * DD + h * DK;
#pragma unroll
            for (int r = 0; r < 4; ++r) {
                const int off = (t & 3) * 4 + r * 16;
                *(float4*)&Vs[key][off] = *(const float4*)(vsrc + off);
            }
        }
        __syncthreads();

        // S = Q · K^T for this thread's 8 keys
        float s[8];
#pragma unroll
        for (int j = 0; j < 8; ++j) s[j] = 0.f;
#pragma unroll 8
        for (int i = 0; i < 64; ++i) {
            const float qv = Qs[qi][i];
            float4 ka = *(const float4*)&Kts[i][c0];
            float4 kb = *(const float4*)&Kts[i][c0 + 4];
            s[0] += qv * ka.x; s[1] += qv * ka.y;
            s[2] += qv * ka.z; s[3] += qv * ka.w;
            s[4] += qv * kb.x; s[5] += qv * kb.y;
            s[6] += qv * kb.z; s[7] += qv * kb.w;
        }

        // angular transform, ^8, stash to LDS, partial row sum
        float lsum = 0.f;
#pragma unroll
        for (int j = 0; j < 8; ++j) {
            float sim = fminf(fmaxf(s[j], -0.999f), 0.999f);
            float sc  = 1.f - acosf(sim) * 0.31830988618379067f;  // 1/pi
            float w   = fmaxf(sc, 1e-6f);
            float w2 = w * w;
            float w4 = w2 * w2;
            float w8 = w4 * w4;
            Ws[qi][c0 + j] = w8;
            lsum += w8;
        }
        lsum += __shfl_xor(lsum, 1);
        lsum += __shfl_xor(lsum, 2);
        lsum += __shfl_xor(lsum, 4);
        rowsum += lsum;
        __syncthreads();

        // O += W_tile @ V_tile
#pragma unroll 8
        for (int k = 0; k < 64; ++k) {
            const float wv = Ws[qi][k];
            float4 va = *(const float4*)&Vs[k][c0];
            float4 vb = *(const float4*)&Vs[k][c0 + 4];
            o[0] += wv * va.x; o[1] += wv * va.y;
            o[2] += wv * va.z; o[3] += wv * va.w;
            o[4] += wv * vb.x; o[5] += wv * vb.y;
            o[6] += wv * vb.z; o[7] += wv * vb.w;
        }
    }

    const float inv = 1.f / (rowsum + 1e-6f);
    float* dst = Oa + (size_t)(b * TT + q0 + qi) * DD + h * DK + c0;
    float4 ra, rb;
    ra.x = o[0] * inv; ra.y = o[1] * inv; ra.z = o[2] * inv; ra.w = o[3] * inv;
    rb.x = o[4] * inv; rb.y = o[5] * inv; rb.z = o[6] * inv; rb.w = o[7] * inv;
    *(float4*)dst       = ra;
    *(float4*)(dst + 4) = rb;
}

// ---------------------------------------------------------------------------
extern "C" void kernel_launch(void* const* d_in, const int* in_sizes, int n_in,
                              void* d_out, int out_size, void* d_ws, size_t ws_size,
                              hipStream_t stream)
{
    const float* x  = (const float*)d_in[0];
    const float* Wq = (const float*)d_in[1];
    const float* Wk = (const float*)d_in[2];
    const float* Wv = (const float*)d_in[3];
    const float* Wo = (const float*)d_in[4];
    const float* bo = (const float*)d_in[5];
    float* out = (float*)d_out;

    const int M = BB * TT;   // 4096
    const int N = DD;        // 1024
    const int K = DD;        // 1024

    const size_t SZ = (size_t)M * DD * sizeof(float);  // 16 MB
    char* ws = (char*)d_ws;
    float* Q0   = (float*)(ws);             // normalized in place
    float* Ktb  = (float*)(ws + SZ);        // K normalized+transposed [b][h][dk][T]
    float* V0   = (float*)(ws + 2 * SZ);
    float* K0   = (float*)(ws + 3 * SZ);    // raw K proj, then reused as attn out
    float* attn = (float*)(ws + 3 * SZ);

    dim3 gB(256);
    dim3 gGemm(N / 64, M / 64);

    // projections
    gemm_nt_kernel<<<gGemm, gB, 0, stream>>>(x, Wq, nullptr, Q0, M, N, K, 0);
    gemm_nt_kernel<<<gGemm, gB, 0, stream>>>(x, Wk, nullptr, K0, M, N, K, 0);
    gemm_nt_kernel<<<gGemm, gB, 0, stream>>>(x, Wv, nullptr, V0, M, N, K, 0);

    // normalize
    const int nSeg = M * HH;                // 65536
    norm_q_kernel<<<nSeg / 4, gB, 0, stream>>>(Q0);
    norm_k_transpose_kernel<<<nSeg / 4, gB, 0, stream>>>(K0, Ktb);

    // fused angular attention (attn aliases K0 — K0 consumed above)
    dim3 gAttn(TT / 32, HH, BB);
    attn_kernel<<<gAttn, gB, 0, stream>>>(Q0, Ktb, V0, attn);

    // output projection + bias
    gemm_nt_kernel<<<gGemm, gB, 0, stream>>>(attn, Wo, bo, out, M, N, K, 1);
}

// Round 2
// 806.079 us; speedup vs baseline: 1.6347x; 1.6347x over previous
//
#include <hip/hip_runtime.h>
#include <hip/hip_bf16.h>
#include <math.h>

// Problem constants
#define BB 2
#define TT 2048
#define DD 1024
#define HH 16
#define DK 64

typedef __attribute__((ext_vector_type(8))) short bf16x8;
typedef __attribute__((ext_vector_type(4))) float f32x4;

static __device__ __forceinline__ short f2bf(float f) {
    __hip_bfloat16 h = __float2bfloat16(f);
    union { __hip_bfloat16 h; short s; } u; u.h = h; return u.s;
}
static __device__ __forceinline__ float bf2f(short s) {
    union { short s; __hip_bfloat16 h; } u; u.s = s; return __bfloat162float(u.h);
}

// ---------------------------------------------------------------------------
// Split-bf16 MFMA GEMM: C[M,N] = A[M,K] @ Bw[N,K]^T (+bias).
// fp32 inputs are split hi/lo bf16 during LDS staging (inline, no extra HBM).
// Block tile 64(M) x 128(N), BK=32. 256 threads = 4 waves in 2x2;
// each wave: 32x64 = 2x4 grid of 16x16x32 MFMA tiles, 3 MFMA per tile pair.
// LDS stride 40 shorts (80 B) -> frag ds_read_b128 conflict-free.
// ---------------------------------------------------------------------------
__global__ __launch_bounds__(256) void gemm_mfma_nt(
    const float* __restrict__ A, const float* __restrict__ Bw,
    const float* __restrict__ bias, float* __restrict__ C,
    int M, int N, int K, int hasBias)
{
    __shared__ short Ah[64][40];
    __shared__ short Al[64][40];
    __shared__ short Bh[128][40];
    __shared__ short Bl[128][40];

    const int t    = threadIdx.x;
    const int m0   = blockIdx.y * 64;
    const int n0   = blockIdx.x * 128;
    const int lane = t & 63;
    const int w    = t >> 6;
    const int wm   = w >> 1;      // 0..1
    const int wn   = w & 1;       // 0..1
    const int l15  = lane & 15;
    const int quad = lane >> 4;

    // staging coords: A tile 64x32 (8 elems/thread), B tile 128x32 (16/thread)
    const int ar = t >> 2, ac = (t & 3) * 8;
    const int br = t >> 1, bc = (t & 1) * 16;

    const float* Aptr = A + (size_t)(m0 + ar) * K + ac;
    const float* Bptr = Bw + (size_t)(n0 + br) * K + bc;

    f32x4 acc[2][4];
#pragma unroll
    for (int i = 0; i < 2; ++i)
#pragma unroll
        for (int j = 0; j < 4; ++j) acc[i][j] = (f32x4)0.f;

    for (int k0 = 0; k0 < K; k0 += 32) {
        float4 a0 = *(const float4*)(Aptr + k0);
        float4 a1 = *(const float4*)(Aptr + k0 + 4);
        float4 b0 = *(const float4*)(Bptr + k0);
        float4 b1 = *(const float4*)(Bptr + k0 + 4);
        float4 b2 = *(const float4*)(Bptr + k0 + 8);
        float4 b3 = *(const float4*)(Bptr + k0 + 12);

        __syncthreads();  // previous chunk's frag reads done
        {
            union { short s[8]; int4 v; } ph, pl;
            float va[8] = {a0.x, a0.y, a0.z, a0.w, a1.x, a1.y, a1.z, a1.w};
#pragma unroll
            for (int j = 0; j < 8; ++j) {
                short h = f2bf(va[j]);
                ph.s[j] = h;
                pl.s[j] = f2bf(va[j] - bf2f(h));
            }
            *(int4*)&Ah[ar][ac] = ph.v;
            *(int4*)&Al[ar][ac] = pl.v;
        }
        {
            union { short s[8]; int4 v; } ph, pl;
            float vb[8] = {b0.x, b0.y, b0.z, b0.w, b1.x, b1.y, b1.z, b1.w};
#pragma unroll
            for (int j = 0; j < 8; ++j) {
                short h = f2bf(vb[j]);
                ph.s[j] = h;
                pl.s[j] = f2bf(vb[j] - bf2f(h));
            }
            *(int4*)&Bh[br][bc] = ph.v;
            *(int4*)&Bl[br][bc] = pl.v;
        }
        {
            union { short s[8]; int4 v; } ph, pl;
            float vb[8] = {b2.x, b2.y, b2.z, b2.w, b3.x, b3.y, b3.z, b3.w};
#pragma unroll
            for (int j = 0; j < 8; ++j) {
                short h = f2bf(vb[j]);
                ph.s[j] = h;
                pl.s[j] = f2bf(vb[j] - bf2f(h));
            }
            *(int4*)&Bh[br][bc + 8] = ph.v;
            *(int4*)&Bl[br][bc + 8] = pl.v;
        }
        __syncthreads();

        bf16x8 ah[2], al[2], bh[4], bl[4];
#pragma unroll
        for (int tm = 0; tm < 2; ++tm) {
            ah[tm] = *(const bf16x8*)&Ah[wm * 32 + tm * 16 + l15][quad * 8];
            al[tm] = *(const bf16x8*)&Al[wm * 32 + tm * 16 + l15][quad * 8];
        }
#pragma unroll
        for (int tn = 0; tn < 4; ++tn) {
            bh[tn] = *(const bf16x8*)&Bh[wn * 64 + tn * 16 + l15][quad * 8];
            bl[tn] = *(const bf16x8*)&Bl[wn * 64 + tn * 16 + l15][quad * 8];
        }
#pragma unroll
        for (int tm = 0; tm < 2; ++tm)
#pragma unroll
            for (int tn = 0; tn < 4; ++tn) {
                acc[tm][tn] = __builtin_amdgcn_mfma_f32_16x16x32_bf16(
                    ah[tm], bh[tn], acc[tm][tn], 0, 0, 0);
                acc[tm][tn] = __builtin_amdgcn_mfma_f32_16x16x32_bf16(
                    ah[tm], bl[tn], acc[tm][tn], 0, 0, 0);
                acc[tm][tn] = __builtin_amdgcn_mfma_f32_16x16x32_bf16(
                    al[tm], bh[tn], acc[tm][tn], 0, 0, 0);
            }
    }

    // epilogue: D row = quad*4 + reg, col = lane&15
#pragma unroll
    for (int tm = 0; tm < 2; ++tm)
#pragma unroll
        for (int tn = 0; tn < 4; ++tn) {
            const int col  = n0 + wn * 64 + tn * 16 + l15;
            const float bv = hasBias ? bias[col] : 0.f;
            const int rowb = m0 + wm * 32 + tm * 16 + quad * 4;
#pragma unroll
            for (int r = 0; r < 4; ++r)
                C[(size_t)(rowb + r) * N + col] = acc[tm][tn][r] + bv;
        }
}

// ---------------------------------------------------------------------------
// Normalize each 64-wide head segment in place (used for Q and K).
// ---------------------------------------------------------------------------
__global__ __launch_bounds__(256) void norm_kernel(float* __restrict__ Q)
{
    const int seg  = blockIdx.x * 4 + (threadIdx.x >> 6);
    const int lane = threadIdx.x & 63;
    const int row  = seg >> 4;   // / H
    const int h    = seg & 15;   // % H
    float* p = Q + (size_t)row * DD + h * DK + lane;
    float v = *p;
    float s = v * v;
    s += __shfl_xor(s, 1);
    s += __shfl_xor(s, 2);
    s += __shfl_xor(s, 4);
    s += __shfl_xor(s, 8);
    s += __shfl_xor(s, 16);
    s += __shfl_xor(s, 32);
    float n = sqrtf(s);
    *p = v / fmaxf(n, 1e-12f);
}

// ---------------------------------------------------------------------------
// Fused angular attention, register-blocked: 64 queries/block, 2 per thread.
// Grid (T/64, H, B), block 256. K loaded row-major (normalized in place)
// and transposed into LDS during staging (conflict-free scalar writes).
// 2 barriers per 64-key tile; Ws round-trip is wave-internal (no 3rd barrier).
// ---------------------------------------------------------------------------
__global__ __launch_bounds__(256) void attn_kernel(
    const float* __restrict__ Qn, const float* __restrict__ Kn,
    const float* __restrict__ V0, float* __restrict__ Oa)
{
    __shared__ float Qs[64][68];   // [q][dim]
    __shared__ float Kts[64][68];  // [dim][key]
    __shared__ float Vs[64][68];   // [key][dim]
    __shared__ float Ws[64][68];   // [q][key]

    const int t  = threadIdx.x;
    const int q0 = blockIdx.x * 64;
    const int h  = blockIdx.y;
    const int b  = blockIdx.z;

    // stage Q tile once
    {
        const int qrow = t >> 2;
        const float* src = Qn + (size_t)(b * TT + q0 + qrow) * DD + h * DK;
#pragma unroll
        for (int r = 0; r < 4; ++r) {
            const int off = (t & 3) * 4 + r * 16;
            *(float4*)&Qs[qrow][off] = *(const float4*)(src + off);
        }
    }

    const int qi0 = t >> 3;        // 0..31
    const int qi1 = qi0 + 32;
    const int c0  = (t & 7) * 8;   // 8 keys per thread

    float o0[8], o1[8];
#pragma unroll
    for (int j = 0; j < 8; ++j) { o0[j] = 0.f; o1[j] = 0.f; }
    float rs0 = 0.f, rs1 = 0.f;

    for (int k0 = 0; k0 < TT; k0 += 64) {
        __syncthreads();  // previous tile fully consumed (also covers Q staging)
        {
            const int key = t >> 2;
            const float* ksrc = Kn + (size_t)(b * TT + k0 + key) * DD + h * DK;
            const float* vsrc = V0 + (size_t)(b * TT + k0 + key) * DD + h * DK;
#pragma unroll
            for (int r = 0; r < 4; ++r) {
                const int off = (t & 3) * 4 + r * 16;
                float4 kv = *(const float4*)(ksrc + off);
                Kts[off + 0][key] = kv.x;
                Kts[off + 1][key] = kv.y;
                Kts[off + 2][key] = kv.z;
                Kts[off + 3][key] = kv.w;
                *(float4*)&Vs[key][off] = *(const float4*)(vsrc + off);
            }
        }
        __syncthreads();

        // S = Q K^T : 2 queries x 8 keys per thread
        float s0[8], s1[8];
#pragma unroll
        for (int j = 0; j < 8; ++j) { s0[j] = 0.f; s1[j] = 0.f; }
#pragma unroll 4
        for (int i = 0; i < 64; ++i) {
            const float qa = Qs[qi0][i];
            const float qb = Qs[qi1][i];
            float4 ka = *(const float4*)&Kts[i][c0];
            float4 kb = *(const float4*)&Kts[i][c0 + 4];
            s0[0] += qa * ka.x; s0[1] += qa * ka.y;
            s0[2] += qa * ka.z; s0[3] += qa * ka.w;
            s0[4] += qa * kb.x; s0[5] += qa * kb.y;
            s0[6] += qa * kb.z; s0[7] += qa * kb.w;
            s1[0] += qb * ka.x; s1[1] += qb * ka.y;
            s1[2] += qb * ka.z; s1[3] += qb * ka.w;
            s1[4] += qb * kb.x; s1[5] += qb * kb.y;
            s1[6] += qb * kb.z; s1[7] += qb * kb.w;
        }

        // angular transform ^8, stash rows (wave-internal), partial row sums
        float ls0 = 0.f, ls1 = 0.f;
        float w80[8], w81[8];
#pragma unroll
        for (int j = 0; j < 8; ++j) {
            float sim = fminf(fmaxf(s0[j], -0.999f), 0.999f);
            float sc  = 1.f - acosf(sim) * 0.31830988618379067f;
            float ww  = fmaxf(sc, 1e-6f);
            float w2 = ww * ww, w4 = w2 * w2;
            w80[j] = w4 * w4;
            ls0 += w80[j];
            sim = fminf(fmaxf(s1[j], -0.999f), 0.999f);
            sc  = 1.f - acosf(sim) * 0.31830988618379067f;
            ww  = fmaxf(sc, 1e-6f);
            w2 = ww * ww; w4 = w2 * w2;
            w81[j] = w4 * w4;
            ls1 += w81[j];
        }
        *(float4*)&Ws[qi0][c0]     = make_float4(w80[0], w80[1], w80[2], w80[3]);
        *(float4*)&Ws[qi0][c0 + 4] = make_float4(w80[4], w80[5], w80[6], w80[7]);
        *(float4*)&Ws[qi1][c0]     = make_float4(w81[0], w81[1], w81[2], w81[3]);
        *(float4*)&Ws[qi1][c0 + 4] = make_float4(w81[4], w81[5], w81[6], w81[7]);
        ls0 += __shfl_xor(ls0, 1);
        ls0 += __shfl_xor(ls0, 2);
        ls0 += __shfl_xor(ls0, 4);
        rs0 += ls0;
        ls1 += __shfl_xor(ls1, 1);
        ls1 += __shfl_xor(ls1, 2);
        ls1 += __shfl_xor(ls1, 4);
        rs1 += ls1;
        // no barrier: Ws rows qi0/qi1 are written and read by the same 8 lanes

        // O += W_tile @ V_tile
#pragma unroll 4
        for (int k = 0; k < 64; ++k) {
            const float wa = Ws[qi0][k];
            const float wb = Ws[qi1][k];
            float4 va = *(const float4*)&Vs[k][c0];
            float4 vb = *(const float4*)&Vs[k][c0 + 4];
            o0[0] += wa * va.x; o0[1] += wa * va.y;
            o0[2] += wa * va.z; o0[3] += wa * va.w;
            o0[4] += wa * vb.x; o0[5] += wa * vb.y;
            o0[6] += wa * vb.z; o0[7] += wa * vb.w;
            o1[0] += wb * va.x; o1[1] += wb * va.y;
            o1[2] += wb * va.z; o1[3] += wb * va.w;
            o1[4] += wb * vb.x; o1[5] += wb * vb.y;
            o1[6] += wb * vb.z; o1[7] += wb * vb.w;
        }
    }

    const float inv0 = 1.f / (rs0 + 1e-6f);
    const float inv1 = 1.f / (rs1 + 1e-6f);
    float* dst0 = Oa + (size_t)(b * TT + q0 + qi0) * DD + h * DK + c0;
    float* dst1 = Oa + (size_t)(b * TT + q0 + qi1) * DD + h * DK + c0;
    *(float4*)dst0       = make_float4(o0[0] * inv0, o0[1] * inv0, o0[2] * inv0, o0[3] * inv0);
    *(float4*)(dst0 + 4) = make_float4(o0[4] * inv0, o0[5] * inv0, o0[6] * inv0, o0[7] * inv0);
    *(float4*)dst1       = make_float4(o1[0] * inv1, o1[1] * inv1, o1[2] * inv1, o1[3] * inv1);
    *(float4*)(dst1 + 4) = make_float4(o1[4] * inv1, o1[5] * inv1, o1[6] * inv1, o1[7] * inv1);
}

// ---------------------------------------------------------------------------
extern "C" void kernel_launch(void* const* d_in, const int* in_sizes, int n_in,
                              void* d_out, int out_size, void* d_ws, size_t ws_size,
                              hipStream_t stream)
{
    const float* x  = (const float*)d_in[0];
    const float* Wq = (const float*)d_in[1];
    const float* Wk = (const float*)d_in[2];
    const float* Wv = (const float*)d_in[3];
    const float* Wo = (const float*)d_in[4];
    const float* bo = (const float*)d_in[5];
    float* out = (float*)d_out;

    const int M = BB * TT;   // 4096
    const int N = DD;        // 1024
    const int K = DD;        // 1024

    const size_t SZ = (size_t)M * DD * sizeof(float);  // 16 MB
    char* ws = (char*)d_ws;
    float* Q0   = (float*)(ws);
    float* K0   = (float*)(ws + SZ);
    float* V0   = (float*)(ws + 2 * SZ);
    float* attn = (float*)(ws + 3 * SZ);

    dim3 gB(256);
    dim3 gGemm(N / 128, M / 64);  // (8, 64)

    gemm_mfma_nt<<<gGemm, gB, 0, stream>>>(x, Wq, nullptr, Q0, M, N, K, 0);
    gemm_mfma_nt<<<gGemm, gB, 0, stream>>>(x, Wk, nullptr, K0, M, N, K, 0);
    gemm_mfma_nt<<<gGemm, gB, 0, stream>>>(x, Wv, nullptr, V0, M, N, K, 0);

    const int nSeg = M * HH;  // 65536
    norm_kernel<<<nSeg / 4, gB, 0, stream>>>(Q0);
    norm_kernel<<<nSeg / 4, gB, 0, stream>>>(K0);

    dim3 gAttn(TT / 64, HH, BB);  // (32, 16, 2)
    attn_kernel<<<gAttn, gB, 0, stream>>>(Q0, K0, V0, attn);

    gemm_mfma_nt<<<gGemm, gB, 0, stream>>>(attn, Wo, bo, out, M, N, K, 1);
}

// Round 3
// 753.162 us; speedup vs baseline: 1.7495x; 1.0703x over previous
//
#include <hip/hip_runtime.h>
#include <hip/hip_bf16.h>
#include <math.h>

// Problem constants
#define BB 2
#define TT 2048
#define DD 1024
#define HH 16
#define DK 64
#define KT 128            // keys per attention tile

typedef __attribute__((ext_vector_type(8))) short bf16x8;
typedef __attribute__((ext_vector_type(4))) float f32x4;

static __device__ __forceinline__ short f2bf(float f) {
    __hip_bfloat16 h = __float2bfloat16(f);
    union { __hip_bfloat16 h; short s; } u; u.h = h; return u.s;
}
static __device__ __forceinline__ float bf2f(short s) {
    union { short s; __hip_bfloat16 h; } u; u.s = s; return __bfloat162float(u.h);
}
static __device__ __forceinline__ int packbf(float a, float b) {
    unsigned int ua = (unsigned short)f2bf(a);
    unsigned int ub = (unsigned short)f2bf(b);
    return (int)(ua | (ub << 16));
}

// ---------------------------------------------------------------------------
// Split-bf16 MFMA GEMM: C[M,N] = A[M,K] @ Bw[N,K]^T (+bias). (unchanged R2)
// ---------------------------------------------------------------------------
__global__ __launch_bounds__(256) void gemm_mfma_nt(
    const float* __restrict__ A, const float* __restrict__ Bw,
    const float* __restrict__ bias, float* __restrict__ C,
    int M, int N, int K, int hasBias)
{
    __shared__ short Ah[64][40];
    __shared__ short Al[64][40];
    __shared__ short Bh[128][40];
    __shared__ short Bl[128][40];

    const int t    = threadIdx.x;
    const int m0   = blockIdx.y * 64;
    const int n0   = blockIdx.x * 128;
    const int lane = t & 63;
    const int w    = t >> 6;
    const int wm   = w >> 1;
    const int wn   = w & 1;
    const int l15  = lane & 15;
    const int quad = lane >> 4;

    const int ar = t >> 2, ac = (t & 3) * 8;
    const int br = t >> 1, bc = (t & 1) * 16;

    const float* Aptr = A + (size_t)(m0 + ar) * K + ac;
    const float* Bptr = Bw + (size_t)(n0 + br) * K + bc;

    f32x4 acc[2][4];
#pragma unroll
    for (int i = 0; i < 2; ++i)
#pragma unroll
        for (int j = 0; j < 4; ++j) acc[i][j] = (f32x4)0.f;

    for (int k0 = 0; k0 < K; k0 += 32) {
        float4 a0 = *(const float4*)(Aptr + k0);
        float4 a1 = *(const float4*)(Aptr + k0 + 4);
        float4 b0 = *(const float4*)(Bptr + k0);
        float4 b1 = *(const float4*)(Bptr + k0 + 4);
        float4 b2 = *(const float4*)(Bptr + k0 + 8);
        float4 b3 = *(const float4*)(Bptr + k0 + 12);

        __syncthreads();
        {
            union { short s[8]; int4 v; } ph, pl;
            float va[8] = {a0.x, a0.y, a0.z, a0.w, a1.x, a1.y, a1.z, a1.w};
#pragma unroll
            for (int j = 0; j < 8; ++j) {
                short h = f2bf(va[j]);
                ph.s[j] = h;
                pl.s[j] = f2bf(va[j] - bf2f(h));
            }
            *(int4*)&Ah[ar][ac] = ph.v;
            *(int4*)&Al[ar][ac] = pl.v;
        }
        {
            union { short s[8]; int4 v; } ph, pl;
            float vb[8] = {b0.x, b0.y, b0.z, b0.w, b1.x, b1.y, b1.z, b1.w};
#pragma unroll
            for (int j = 0; j < 8; ++j) {
                short h = f2bf(vb[j]);
                ph.s[j] = h;
                pl.s[j] = f2bf(vb[j] - bf2f(h));
            }
            *(int4*)&Bh[br][bc] = ph.v;
            *(int4*)&Bl[br][bc] = pl.v;
        }
        {
            union { short s[8]; int4 v; } ph, pl;
            float vb[8] = {b2.x, b2.y, b2.z, b2.w, b3.x, b3.y, b3.z, b3.w};
#pragma unroll
            for (int j = 0; j < 8; ++j) {
                short h = f2bf(vb[j]);
                ph.s[j] = h;
                pl.s[j] = f2bf(vb[j] - bf2f(h));
            }
            *(int4*)&Bh[br][bc + 8] = ph.v;
            *(int4*)&Bl[br][bc + 8] = pl.v;
        }
        __syncthreads();

        bf16x8 ah[2], al[2], bh[4], bl[4];
#pragma unroll
        for (int tm = 0; tm < 2; ++tm) {
            ah[tm] = *(const bf16x8*)&Ah[wm * 32 + tm * 16 + l15][quad * 8];
            al[tm] = *(const bf16x8*)&Al[wm * 32 + tm * 16 + l15][quad * 8];
        }
#pragma unroll
        for (int tn = 0; tn < 4; ++tn) {
            bh[tn] = *(const bf16x8*)&Bh[wn * 64 + tn * 16 + l15][quad * 8];
            bl[tn] = *(const bf16x8*)&Bl[wn * 64 + tn * 16 + l15][quad * 8];
        }
#pragma unroll
        for (int tm = 0; tm < 2; ++tm)
#pragma unroll
            for (int tn = 0; tn < 4; ++tn) {
                acc[tm][tn] = __builtin_amdgcn_mfma_f32_16x16x32_bf16(
                    ah[tm], bh[tn], acc[tm][tn], 0, 0, 0);
                acc[tm][tn] = __builtin_amdgcn_mfma_f32_16x16x32_bf16(
                    ah[tm], bl[tn], acc[tm][tn], 0, 0, 0);
                acc[tm][tn] = __builtin_amdgcn_mfma_f32_16x16x32_bf16(
                    al[tm], bh[tn], acc[tm][tn], 0, 0, 0);
            }
    }

#pragma unroll
    for (int tm = 0; tm < 2; ++tm)
#pragma unroll
        for (int tn = 0; tn < 4; ++tn) {
            const int col  = n0 + wn * 64 + tn * 16 + l15;
            const float bv = hasBias ? bias[col] : 0.f;
            const int rowb = m0 + wm * 32 + tm * 16 + quad * 4;
#pragma unroll
            for (int r = 0; r < 4; ++r)
                C[(size_t)(rowb + r) * N + col] = acc[tm][tn][r] + bv;
        }
}

// ---------------------------------------------------------------------------
// Normalize each 64-wide head segment; emit hi/lo split bf16 at [b][h][t][dk].
// ---------------------------------------------------------------------------
__global__ __launch_bounds__(256) void normsplit_kernel(
    const float* __restrict__ X, short* __restrict__ Hi, short* __restrict__ Lo)
{
    const int seg  = blockIdx.x * 4 + (threadIdx.x >> 6);
    const int lane = threadIdx.x & 63;
    const int row  = seg >> 4;   // b*T + t
    const int h    = seg & 15;
    float v = X[(size_t)row * DD + h * DK + lane];
    float s = v * v;
    s += __shfl_xor(s, 1);
    s += __shfl_xor(s, 2);
    s += __shfl_xor(s, 4);
    s += __shfl_xor(s, 8);
    s += __shfl_xor(s, 16);
    s += __shfl_xor(s, 32);
    float n = sqrtf(s);
    float vn = v / fmaxf(n, 1e-12f);
    const int b  = row >> 11;
    const int tt = row & 2047;
    size_t o = ((size_t)(b * HH + h) * TT + tt) * DK + lane;
    short hv = f2bf(vn);
    Hi[o] = hv;
    Lo[o] = f2bf(vn - bf2f(hv));
}

// ---------------------------------------------------------------------------
// V -> bf16 transposed [b][h][d][T].
// ---------------------------------------------------------------------------
__global__ __launch_bounds__(256) void vtrans_kernel(
    const float* __restrict__ V0, short* __restrict__ Vt)
{
    __shared__ short Vtmp[64][72];
    const int t  = threadIdx.x;
    const int t0 = blockIdx.x * 64;
    const int h  = blockIdx.y;
    const int b  = blockIdx.z;

    {
        const int i  = t >> 2;            // token row 0..63
        const int jc = (t & 3) * 16;      // dim chunk
        const float* src = V0 + (size_t)(b * TT + t0 + i) * DD + h * DK + jc;
#pragma unroll
        for (int c = 0; c < 4; ++c) {
            float4 v = *(const float4*)(src + c * 4);
            Vtmp[jc + c * 4 + 0][i] = f2bf(v.x);
            Vtmp[jc + c * 4 + 1][i] = f2bf(v.y);
            Vtmp[jc + c * 4 + 2][i] = f2bf(v.z);
            Vtmp[jc + c * 4 + 3][i] = f2bf(v.w);
        }
    }
    __syncthreads();
    {
        const int d  = t >> 2;
        const int kc = (t & 3) * 16;
        short* dst = Vt + ((size_t)((b * HH + h) * DK + d)) * TT + t0 + kc;
        *(int4*)(dst)     = *(const int4*)&Vtmp[d][kc];
        *(int4*)(dst + 8) = *(const int4*)&Vtmp[d][kc + 8];
    }
}

// ---------------------------------------------------------------------------
// MFMA angular attention. Grid (T/64, H, B), 256 threads (4 waves).
// Block: 64 queries; key tiles of 128; wave w owns keys [w*32, w*32+32).
// S^T = K·Q^T via 16x16x32 MFMA (split hi/lo, 3 products). Transform in
// C-regs. W pairs -> per-wave LDS region -> A-frags for PV MFMA.
// Each wave accumulates partial O[64q x 64d] over its keys; cross-wave
// reduction through LDS at the end. Rowsum kept fp32 in registers.
// ---------------------------------------------------------------------------
__global__ __launch_bounds__(256, 2) void attn_kernel(
    const short* __restrict__ Qhi, const short* __restrict__ Qlo,
    const short* __restrict__ Khi_g, const short* __restrict__ Klo_g,
    const short* __restrict__ Vt_g, float* __restrict__ Oa)
{
    __shared__ union {
        short k[2][128][72];          // [hi/lo][key][dk]
        float obuf[64][68];           // epilogue O reduction
    } U;
    __shared__ short Vts[64][136];    // [d][key]
    __shared__ int   Wls[4][64][20];  // per-wave W pairs: [w][q][keypair]
    __shared__ float Rbuf[4][64];
    __shared__ float Rfin[64];

    const int t    = threadIdx.x;
    const int lane = t & 63;
    const int w    = t >> 6;
    const int l15  = lane & 15;
    const int quad = lane >> 4;
    const int q0   = blockIdx.x * 64;
    const int h    = blockIdx.y;
    const int b    = blockIdx.z;
    const size_t bh = (size_t)(b * HH + h);

    // hoist Q B-frags (q = 16*t4 + l15, k = s*32 + quad*8)
    bf16x8 qf[4][2][2];
    {
        const short* qh = Qhi + (bh * TT + q0) * DK;
        const short* ql = Qlo + (bh * TT + q0) * DK;
#pragma unroll
        for (int t4 = 0; t4 < 4; ++t4)
#pragma unroll
            for (int s = 0; s < 2; ++s) {
                size_t off = (size_t)(16 * t4 + l15) * DK + s * 32 + quad * 8;
                qf[t4][s][0] = *(const bf16x8*)(qh + off);
                qf[t4][s][1] = *(const bf16x8*)(ql + off);
            }
    }

    f32x4 acc[4][4];   // [qt][nd] partial O
#pragma unroll
    for (int i = 0; i < 4; ++i)
#pragma unroll
        for (int j = 0; j < 4; ++j) acc[i][j] = (f32x4)0.f;
    float partial[4] = {0.f, 0.f, 0.f, 0.f};

    const short* kh_g = Khi_g + bh * TT * DK;
    const short* kl_g = Klo_g + bh * TT * DK;
    const short* vt_g = Vt_g + bh * (size_t)DK * TT;

    const int srow = t >> 1;          // K stage row 0..127
    const int scol = (t & 1) * 32;    // shorts
    const int vrow = t >> 2;          // V stage d 0..63
    const int vcol = (t & 3) * 32;    // shorts

    for (int k0 = 0; k0 < TT; k0 += KT) {
        int4 kh[4], kl[4], vv[4];
        {
            const short* kp = kh_g + (size_t)(k0 + srow) * DK + scol;
            const short* lp = kl_g + (size_t)(k0 + srow) * DK + scol;
            const short* vp = vt_g + (size_t)vrow * TT + k0 + vcol;
#pragma unroll
            for (int c = 0; c < 4; ++c) {
                kh[c] = *(const int4*)(kp + c * 8);
                kl[c] = *(const int4*)(lp + c * 8);
                vv[c] = *(const int4*)(vp + c * 8);
            }
        }
        __syncthreads();
#pragma unroll
        for (int c = 0; c < 4; ++c) {
            *(int4*)&U.k[0][srow][scol + c * 8] = kh[c];
            *(int4*)&U.k[1][srow][scol + c * 8] = kl[c];
            *(int4*)&Vts[vrow][vcol + c * 8]    = vv[c];
        }
        __syncthreads();

        // S^T tiles + transform; wave keys [w*32, w*32+32)
#pragma unroll
        for (int mt = 0; mt < 2; ++mt) {
            f32x4 c_[4];
#pragma unroll
            for (int qt = 0; qt < 4; ++qt) c_[qt] = (f32x4)0.f;
            const int key = w * 32 + mt * 16 + l15;
#pragma unroll
            for (int s = 0; s < 2; ++s) {
                bf16x8 ah = *(const bf16x8*)&U.k[0][key][s * 32 + quad * 8];
                bf16x8 al = *(const bf16x8*)&U.k[1][key][s * 32 + quad * 8];
#pragma unroll
                for (int qt = 0; qt < 4; ++qt) {
                    c_[qt] = __builtin_amdgcn_mfma_f32_16x16x32_bf16(
                        ah, qf[qt][s][0], c_[qt], 0, 0, 0);
                    c_[qt] = __builtin_amdgcn_mfma_f32_16x16x32_bf16(
                        ah, qf[qt][s][1], c_[qt], 0, 0, 0);
                    c_[qt] = __builtin_amdgcn_mfma_f32_16x16x32_bf16(
                        al, qf[qt][s][0], c_[qt], 0, 0, 0);
                }
            }
            // angular transform, pow8, write packed pairs to per-wave LDS
#pragma unroll
            for (int qt = 0; qt < 4; ++qt) {
                float w8[4];
#pragma unroll
                for (int r = 0; r < 4; ++r) {
                    float sim = fminf(fmaxf(c_[qt][r], -0.999f), 0.999f);
                    float sc  = 1.f - acosf(sim) * 0.31830988618379067f;
                    float ww  = fmaxf(sc, 1e-6f);
                    float w2 = ww * ww, w4 = w2 * w2;
                    w8[r] = w4 * w4;
                    partial[qt] += w8[r];
                }
                int2 pk;
                pk.x = packbf(w8[0], w8[1]);
                pk.y = packbf(w8[2], w8[3]);
                *(int2*)&Wls[w][16 * qt + l15][mt * 8 + 2 * quad] = pk;
            }
        }

        // PV: O[64q x 64d] partial over wave's 32 keys (1 kstep of 32)
#pragma unroll
        for (int qt = 0; qt < 4; ++qt) {
            union { int4 i4; bf16x8 v; } au;
            au.i4 = *(const int4*)&Wls[w][16 * qt + l15][quad * 4];
#pragma unroll
            for (int nd = 0; nd < 4; ++nd) {
                bf16x8 bv = *(const bf16x8*)&Vts[nd * 16 + l15][w * 32 + quad * 8];
                acc[qt][nd] = __builtin_amdgcn_mfma_f32_16x16x32_bf16(
                    au.v, bv, acc[qt][nd], 0, 0, 0);
            }
        }
    }

    // rowsum reduce: per q = 16*qt + l15
#pragma unroll
    for (int qt = 0; qt < 4; ++qt) {
        float p = partial[qt];
        p += __shfl_xor(p, 16);
        p += __shfl_xor(p, 32);
        if (quad == 0) Rbuf[w][qt * 16 + l15] = p;
    }
    __syncthreads();
    if (t < 64) {
        float s = Rbuf[0][t] + Rbuf[1][t] + Rbuf[2][t] + Rbuf[3][t];
        Rfin[t] = 1.f / (s + 1e-6f);
    }

    // cross-wave O reduction into U.obuf (rotating q-tile ownership)
    for (int rds = 0; rds < 4; ++rds) {
        __syncthreads();
        const int myqt = (w + rds) & 3;
#pragma unroll
        for (int nd = 0; nd < 4; ++nd)
#pragma unroll
            for (int r = 0; r < 4; ++r) {
                float* p = &U.obuf[myqt * 16 + quad * 4 + r][nd * 16 + l15];
                float v = acc[myqt][nd][r];
                if (rds == 0) *p = v; else *p += v;
            }
    }
    __syncthreads();

    // final write: row = t>>2, 16 cols per thread, scaled by 1/rowsum
    {
        const int row   = t >> 2;
        const int chunk = (t & 3) * 16;
        const float inv = Rfin[row];
        float* dst = Oa + (size_t)(b * TT + q0 + row) * DD + h * DK + chunk;
#pragma unroll
        for (int c = 0; c < 4; ++c) {
            float4 v = *(const float4*)&U.obuf[row][chunk + c * 4];
            v.x *= inv; v.y *= inv; v.z *= inv; v.w *= inv;
            *(float4*)(dst + c * 4) = v;
        }
    }
}

// ---------------------------------------------------------------------------
extern "C" void kernel_launch(void* const* d_in, const int* in_sizes, int n_in,
                              void* d_out, int out_size, void* d_ws, size_t ws_size,
                              hipStream_t stream)
{
    const float* x  = (const float*)d_in[0];
    const float* Wq = (const float*)d_in[1];
    const float* Wk = (const float*)d_in[2];
    const float* Wv = (const float*)d_in[3];
    const float* Wo = (const float*)d_in[4];
    const float* bo = (const float*)d_in[5];
    float* out = (float*)d_out;

    const int M = BB * TT;   // 4096
    const int N = DD;
    const int K = DD;

    const size_t MB = 1024 * 1024;
    char* ws = (char*)d_ws;
    float* Q0   = (float*)(ws);              // [0,16M)
    float* K0   = (float*)(ws + 16 * MB);    // [16M,32M)
    float* V0   = (float*)(ws + 32 * MB);    // [32M,48M)
    short* Qhi  = (short*)(ws + 48 * MB);    // [48M,56M)
    short* Qlo  = (short*)(ws + 56 * MB);    // [56M,64M)
    short* Khi  = (short*)(ws);              // reuse Q0 after q-normsplit
    short* Klo  = (short*)(ws + 8 * MB);
    short* Vt   = (short*)(ws + 16 * MB);    // reuse K0 after k-normsplit
    float* attn = (float*)(ws + 32 * MB);    // reuse V0 after vtrans

    dim3 gB(256);
    dim3 gGemm(N / 128, M / 64);

    gemm_mfma_nt<<<gGemm, gB, 0, stream>>>(x, Wq, nullptr, Q0, M, N, K, 0);
    gemm_mfma_nt<<<gGemm, gB, 0, stream>>>(x, Wk, nullptr, K0, M, N, K, 0);
    gemm_mfma_nt<<<gGemm, gB, 0, stream>>>(x, Wv, nullptr, V0, M, N, K, 0);

    const int nSeg = M * HH;  // 65536
    normsplit_kernel<<<nSeg / 4, gB, 0, stream>>>(Q0, Qhi, Qlo);
    normsplit_kernel<<<nSeg / 4, gB, 0, stream>>>(K0, Khi, Klo);
    vtrans_kernel<<<dim3(TT / 64, HH, BB), gB, 0, stream>>>(V0, Vt);

    attn_kernel<<<dim3(TT / 64, HH, BB), gB, 0, stream>>>(Qhi, Qlo, Khi, Klo, Vt, attn);

    gemm_mfma_nt<<<gGemm, gB, 0, stream>>>(attn, Wo, bo, out, M, N, K, 1);
}